// Round 9
// baseline (442.970 us; speedup 1.0000x reference)
//
#include <hip/hip_runtime.h>
#include <hip/hip_bf16.h>
#include <math.h>

// Problem constants
#define HID  1024
#define NEXP 8
#define CAP  1536
#define NTOK 4096   // B*S

// Output layout (fp32), flat in reference return order
#define DISP_OFF 0ull
#define COMB_OFF 50331648ull
#define RP_OFF   100663296ull
#define AUX_OFF  100696064ull

typedef float f32x4 __attribute__((ext_vector_type(4)));
typedef short s16x8 __attribute__((ext_vector_type(8)));
typedef unsigned short u16;

// ws layout (float units): part[16][4096][8] | XH | XM | WH | WM (bf16 pairs)
#define PART_F 524288
#define OXH_F  526400
#define OXM_F  2623552
#define OWH_F  4720704
#define OWM_F  5244992

// fp32 -> (bf16 hi, bf16 mid), RNE both
__device__ __forceinline__ void cvt8(const float4 v0, const float4 v1, s16x8& hi, s16x8& mi)
{
    float f[8] = {v0.x, v0.y, v0.z, v0.w, v1.x, v1.y, v1.z, v1.w};
#pragma unroll
    for (int i = 0; i < 8; ++i) {
        __hip_bfloat16 h = __float2bfloat16(f[i]);
        float fh = __bfloat162float(h);
        __hip_bfloat16 m = __float2bfloat16(f[i] - fh);
        hi[i] = (short)__builtin_bit_cast(unsigned short, h);
        mi[i] = (short)__builtin_bit_cast(unsigned short, m);
    }
}

__device__ __forceinline__ void gload16(const void* g, void* l)
{
    __builtin_amdgcn_global_load_lds(
        (const __attribute__((address_space(1))) unsigned int*)g,
        (__attribute__((address_space(3))) unsigned int*)l, 16, 0, 0);
}

// ---------------- Prep: fp32 -> bf16 hi/mid split of x and w1 ----------------
__global__ __launch_bounds__(256) void prep_kernel(
    const float* __restrict__ X, const float* __restrict__ W1, float* __restrict__ ws)
{
    const int g = blockIdx.x * 256 + threadIdx.x;
    const float* src;
    u16 *dh, *dm;
    int idx;
    if (g < 524288) { src = X;  dh = (u16*)(ws + OXH_F); dm = (u16*)(ws + OXM_F); idx = g; }
    else            { src = W1; dh = (u16*)(ws + OWH_F); dm = (u16*)(ws + OWM_F); idx = g - 524288; }
    float4 v0 = *(const float4*)(src + (size_t)idx * 8);
    float4 v1 = *(const float4*)(src + (size_t)idx * 8 + 4);
    s16x8 hi, mi;
    cvt8(v0, v1, hi, mi);
    *(s16x8*)(dh + (size_t)idx * 8) = hi;
    *(s16x8*)(dm + (size_t)idx * 8) = mi;
}

// ---------------- Fused: GEMM + interleaved 402.7 MB zero-fill ----------------
// 256 blocks x 512 threads. Tile 128x128, BK=32, 8 waves in 4x2 (each wave
// 32 rows x 64 cols, acc[2][4]), double-buffered 64 KB LDS -> 1 block/CU,
// 2 waves/SIMD. Each thread issues 6 nontemporal zero-stores per K-step
// (32*6*512*16B*256 = 402.7 MB total) on the VMEM pipe under the MFMA phase.
// Every 16x16 output fragment gets the identical MFMA sequence as the R8
// kernel (same K order, same 3-pass chain) -> bitwise-identical logits.
// Swizzle: 16B chunk c of row r at slot c^(r&3); gload source pre-swizzled.
__global__ __launch_bounds__(512) void fused_kernel(
    const float* __restrict__ B1, const float* __restrict__ W2,
    float* __restrict__ ws, float* __restrict__ out)
{
    __shared__ s16x8 L[2][4][128][4];   // [buf][Ah,Am,Bh,Bm][row][slot16B] = 64 KB
    const int tid = threadIdx.x, bid = blockIdx.x;

    const int n0 = (bid & 7) * 128;
    const int m0 = (bid >> 3) * 128;
    const int wave = tid >> 6, lane = tid & 63;
    const int wr = wave >> 1, wc = wave & 1;    // 4x2 wave grid
    const int fr = lane & 15, fk = lane >> 4;

    const u16* XH = (const u16*)(ws + OXH_F);
    const u16* XM = (const u16*)(ws + OXM_F);
    const u16* WH = (const u16*)(ws + OWH_F);
    const u16* WM = (const u16*)(ws + OWM_F);

    // zero-role pointer: block owns 98304 f32x4 (1.57 MB)
    f32x4* zp = (f32x4*)out + (size_t)bid * 98304 + tid;
    const f32x4 zv = (f32x4)0.0f;

    // staging: wave stages subtile st (0:Ah 1:Am 2:Bh 3:Bm), half hf (64 rows).
    // pass i covers rows hf*64+i*16 .. +15; lane l -> row +(l>>2), slot l&3,
    // which must hold global 16B chunk (l&3)^(row&3); row&3 == (l>>2)&3.
    const int st = wave >> 1, hf = wave & 1;
    const int sr4 = lane >> 2;
    const int cg  = (lane & 3) ^ (sr4 & 3);
    const u16* sb = (st >= 2)
        ? (((st == 3) ? WM : WH) + (size_t)(n0 + hf * 64 + sr4) * HID + cg * 8)
        : (((st == 1) ? XM : XH) + (size_t)(m0 + hf * 64 + sr4) * HID + cg * 8);
    char* db0 = (char*)&L[0][st][0][0] + hf * 4096;   // + i*1024 per pass, + b*32768 per buf

    f32x4 acc[2][4];
#pragma unroll
    for (int i = 0; i < 2; ++i)
#pragma unroll
        for (int j = 0; j < 4; ++j) acc[i][j] = (f32x4)0.0f;

    // prologue: stage tile 0 into buf 0 (4 passes x 1 KB per wave)
#pragma unroll
    for (int i = 0; i < 4; ++i)
        gload16(sb + (size_t)i * 16 * HID, db0 + i * 1024);
    __syncthreads();    // tile 0 resident

    for (int kk = 0; kk < 32; ++kk) {
        const int b = kk & 1;
        if (kk + 1 < 32) {
            // next tile's staging; latency hides under this tile's MFMAs
            const u16* s = sb + (size_t)(kk + 1) * 32;
            char* d = db0 + (b ^ 1) * 32768;
#pragma unroll
            for (int i = 0; i < 4; ++i)
                gload16(s + (size_t)i * 16 * HID, d + i * 1024);
        }
        // zero-role: 6 stores on the VMEM pipe, drained at the step barrier
#pragma unroll
        for (int i2 = 0; i2 < 6; ++i2) {
            __builtin_nontemporal_store(zv, zp);
            zp += 512;
        }

        const s16x8 (*LAh)[4] = L[b][0];
        const s16x8 (*LAm)[4] = L[b][1];
        const s16x8 (*LBh)[4] = L[b][2];
        const s16x8 (*LBm)[4] = L[b][3];
        const int sl = fk ^ (fr & 3);          // row&3 == fr&3 for all frag rows
        s16x8 bh[4], bm[4];
#pragma unroll
        for (int j = 0; j < 4; ++j) {
            const int rb = wc * 64 + j * 16 + fr;
            bh[j] = LBh[rb][sl];
            bm[j] = LBm[rb][sl];
        }
#pragma unroll
        for (int i = 0; i < 2; ++i) {
            const int ra = wr * 32 + i * 16 + fr;
            s16x8 ah = LAh[ra][sl];
            s16x8 am = LAm[ra][sl];
#pragma unroll
            for (int j = 0; j < 4; ++j) {
                acc[i][j] = __builtin_amdgcn_mfma_f32_16x16x32_bf16(ah, bh[j], acc[i][j], 0, 0, 0);
                acc[i][j] = __builtin_amdgcn_mfma_f32_16x16x32_bf16(ah, bm[j], acc[i][j], 0, 0, 0);
                acc[i][j] = __builtin_amdgcn_mfma_f32_16x16x32_bf16(am, bh[j], acc[i][j], 0, 0, 0);
            }
        }
        __syncthreads();   // next tile staged + stores drained + buf b reads done
    }

    // ---- epilogue: bias+relu, layer-2 partials over this wave's 64 cols ----
    // C/D: lane holds D[fk*4+r][fr] per 16x16 frag
    const int colbase = n0 + wc * 64 + fr;
#pragma unroll
    for (int j = 0; j < 4; ++j) {
        const float bj = B1[colbase + j * 16];
#pragma unroll
        for (int i = 0; i < 2; ++i)
#pragma unroll
            for (int r = 0; r < 4; ++r)
                acc[i][j][r] = fmaxf(acc[i][j][r] + bj, 0.f);
    }

    const int slice = (bid & 7) * 2 + wc;      // 16 col-slices of 64 (same as R8)
    float* pbase = ws + ((size_t)slice * NTOK + (m0 + wr * 32 + fk * 4)) * NEXP;
#pragma unroll
    for (int e = 0; e < 8; ++e) {
        const float w20 = W2[e * HID + colbase];
        const float w21 = W2[e * HID + colbase + 16];
        const float w22 = W2[e * HID + colbase + 32];
        const float w23 = W2[e * HID + colbase + 48];
        float pe[8];
#pragma unroll
        for (int i = 0; i < 2; ++i)
#pragma unroll
            for (int r = 0; r < 4; ++r)
                pe[i * 4 + r] = acc[i][0][r] * w20 + acc[i][1][r] * w21 +
                                acc[i][2][r] * w22 + acc[i][3][r] * w23;
#pragma unroll
        for (int m = 1; m <= 8; m <<= 1)
#pragma unroll
            for (int q = 0; q < 8; ++q)
                pe[q] += __shfl_xor(pe[q], m, 64);
        if (fr == 0) {
#pragma unroll
            for (int i = 0; i < 2; ++i)
#pragma unroll
                for (int r = 0; r < 4; ++r)
                    pbase[(size_t)(i * 16 + r) * NEXP + e] = pe[i * 4 + r];
        }
    }
}

// ---------------- Router: sum partials, softmax, top-2, scatter ----------------
__global__ __launch_bounds__(256) void router2_kernel(
    const float* __restrict__ ws, const float* __restrict__ B2, float* __restrict__ out)
{
    const int t = blockIdx.x * 256 + threadIdx.x;
    float lg[8];
#pragma unroll
    for (int e = 0; e < 8; ++e) lg[e] = 0.f;
#pragma unroll
    for (int s = 0; s < 16; ++s) {      // fixed order -> deterministic
        const float* p = ws + ((size_t)s * NTOK + t) * NEXP;
        f32x4 v0 = *(const f32x4*)p;
        f32x4 v1 = *(const f32x4*)(p + 4);
        lg[0] += v0.x; lg[1] += v0.y; lg[2] += v0.z; lg[3] += v0.w;
        lg[4] += v1.x; lg[5] += v1.y; lg[6] += v1.z; lg[7] += v1.w;
    }
#pragma unroll
    for (int e = 0; e < 8; ++e) lg[e] += B2[e];

    float mx = lg[0];
#pragma unroll
    for (int e = 1; e < 8; ++e) mx = fmaxf(mx, lg[e]);
    float pr[8], s = 0.f;
#pragma unroll
    for (int e = 0; e < 8; ++e) { pr[e] = expf(lg[e] - mx); s += pr[e]; }
    const float inv = 1.f / s;
#pragma unroll
    for (int e = 0; e < 8; ++e) pr[e] *= inv;

    // top-2 (strict > : lowest index wins exact ties, matching lax.top_k)
    int e1 = 0; float p1 = pr[0];
#pragma unroll
    for (int e = 1; e < 8; ++e) if (pr[e] > p1) { p1 = pr[e]; e1 = e; }
    int e2 = -1; float p2 = -1.f;
#pragma unroll
    for (int e = 0; e < 8; ++e) if (e != e1 && pr[e] > p2) { p2 = pr[e]; e2 = e; }

    const float invs = 1.f / (p1 + p2);
    float* rp = out + RP_OFF + (size_t)t * NEXP;
    f32x4 o0 = {pr[0], pr[1], pr[2], pr[3]};
    f32x4 o1 = {pr[4], pr[5], pr[6], pr[7]};
    *(f32x4*)rp = o0; *(f32x4*)(rp + 4) = o1;

    const size_t base = (size_t)t * NEXP;
    out[DISP_OFF + (base + e1) * CAP] = 1.0f;
    out[DISP_OFF + (base + e2) * CAP] = 1.0f;
    out[COMB_OFF + (base + e1) * CAP] = p1 * invs;
    out[COMB_OFF + (base + e2) * CAP] = p2 * invs;
}

// ---------------- Aux loss ----------------
__global__ __launch_bounds__(256) void aux_kernel(float* __restrict__ out)
{
    __shared__ float sm[NEXP][257];
    const int tid = threadIdx.x;
    float s[NEXP];
#pragma unroll
    for (int e = 0; e < 8; ++e) s[e] = 0.f;
    const float* rp = out + RP_OFF;
    for (int t = tid; t < NTOK; t += 256) {
        f32x4 v0 = *(const f32x4*)&rp[(size_t)t * NEXP];
        f32x4 v1 = *(const f32x4*)&rp[(size_t)t * NEXP + 4];
        s[0] += v0.x; s[1] += v0.y; s[2] += v0.z; s[3] += v0.w;
        s[4] += v1.x; s[5] += v1.y; s[6] += v1.z; s[7] += v1.w;
    }
#pragma unroll
    for (int e = 0; e < 8; ++e) sm[e][tid] = s[e];
    __syncthreads();
    for (int st = 128; st > 0; st >>= 1) {
        if (tid < st) {
#pragma unroll
            for (int e = 0; e < 8; ++e) sm[e][tid] += sm[e][tid + st];
        }
        __syncthreads();
    }
    if (tid == 0) {
        float loss = 0.f;
#pragma unroll
        for (int e = 0; e < 8; ++e) {
            float m = sm[e][0] * (1.0f / NTOK);
            loss += m * logf(m * (float)NEXP + 1e-9f);
        }
        out[AUX_OFF] = loss;
    }
}

extern "C" void kernel_launch(void* const* d_in, const int* in_sizes, int n_in,
                              void* d_out, int out_size, void* d_ws, size_t ws_size,
                              hipStream_t stream)
{
    const float* x  = (const float*)d_in[0];
    const float* w1 = (const float*)d_in[1];
    const float* b1 = (const float*)d_in[2];
    const float* w2 = (const float*)d_in[3];
    const float* b2 = (const float*)d_in[4];
    float* out = (float*)d_out;
    float* ws  = (float*)d_ws;     // ~23 MB used

    prep_kernel<<<2560, 256, 0, stream>>>(x, w1, ws);
    // 256 blocks x 512 thr: every CU runs one block doing GEMM (2 waves/SIMD)
    // with the 402.7 MB zero-fill interleaved on the VMEM pipe.
    fused_kernel<<<256, 512, 0, stream>>>(b1, w2, ws, out);
    router2_kernel<<<16, 256, 0, stream>>>(ws, b2, out);
    aux_kernel<<<1, 256, 0, stream>>>(out);
}

// Round 12
// 436.488 us; speedup vs baseline: 1.0149x; 1.0149x over previous
//
#include <hip/hip_runtime.h>
#include <hip/hip_bf16.h>
#include <math.h>

// Problem constants
#define HID  1024
#define NEXP 8
#define CAP  1536
#define NTOK 4096   // B*S

// Output layout (fp32), flat in reference return order
#define DISP_OFF 0ull
#define COMB_OFF 50331648ull
#define RP_OFF   100663296ull
#define AUX_OFF  100696064ull

typedef float f32x4 __attribute__((ext_vector_type(4)));
typedef short s16x8 __attribute__((ext_vector_type(8)));
typedef unsigned short u16;

// ws layout (float units): part[16][4096][8] | XH | XM | WH | WM (bf16 pairs)
#define PART_F 524288
#define OXH_F  526400
#define OXM_F  2623552
#define OWH_F  4720704
#define OWM_F  5244992

// fp32 -> (bf16 hi, bf16 mid), RNE both
__device__ __forceinline__ void cvt8(const float4 v0, const float4 v1, s16x8& hi, s16x8& mi)
{
    float f[8] = {v0.x, v0.y, v0.z, v0.w, v1.x, v1.y, v1.z, v1.w};
#pragma unroll
    for (int i = 0; i < 8; ++i) {
        __hip_bfloat16 h = __float2bfloat16(f[i]);
        float fh = __bfloat162float(h);
        __hip_bfloat16 m = __float2bfloat16(f[i] - fh);
        hi[i] = (short)__builtin_bit_cast(unsigned short, h);
        mi[i] = (short)__builtin_bit_cast(unsigned short, m);
    }
}

__device__ __forceinline__ void gload16(const void* g, void* l)
{
    __builtin_amdgcn_global_load_lds(
        (const __attribute__((address_space(1))) unsigned int*)g,
        (__attribute__((address_space(3))) unsigned int*)l, 16, 0, 0);
}

// ---------------- Prep: fp32 -> bf16 hi/mid split of x and w1 ----------------
__global__ __launch_bounds__(256) void prep_kernel(
    const float* __restrict__ X, const float* __restrict__ W1, float* __restrict__ ws)
{
    const int g = blockIdx.x * 256 + threadIdx.x;
    const float* src;
    u16 *dh, *dm;
    int idx;
    if (g < 524288) { src = X;  dh = (u16*)(ws + OXH_F); dm = (u16*)(ws + OXM_F); idx = g; }
    else            { src = W1; dh = (u16*)(ws + OWH_F); dm = (u16*)(ws + OWM_F); idx = g - 524288; }
    float4 v0 = *(const float4*)(src + (size_t)idx * 8);
    float4 v1 = *(const float4*)(src + (size_t)idx * 8 + 4);
    s16x8 hi, mi;
    cvt8(v0, v1, hi, mi);
    *(s16x8*)(dh + (size_t)idx * 8) = hi;
    *(s16x8*)(dm + (size_t)idx * 8) = mi;
}

// ---------------- Fused: GEMM (bid<256) + 402.7 MB zero-fill (bid>=256) --------
// GEMM: tile 128x128, BK=32, 8 waves in 4x2 (32 rows x 64 cols each, acc[2][4]),
// double-buffered 64 KB LDS, 512 thr -> 2 waves/SIMD; co-resident with one
// 512-thr zero block per CU (64+64 KB LDS, 16 waves).
// XCD-clustered tile map: workgroup->XCD round-robins bid%8, so cluster
// c = bid&7 (one XCD) owns 4 m-tiles x 8 n-slices -> per-XCD working set
// ~6 MB (2 MB X + 4.2 MB W), L2-resident; X is no longer re-fetched by all
// 8 XCDs (134 MB -> ~17 MB cross-fabric). Pure permutation of tile
// assignment: per-fragment MFMA chain identical -> bitwise-identical output.
// Swizzle: 16B chunk c of row r at slot c^(r&3); gload source pre-swizzled.
__global__ __launch_bounds__(512) void fused_kernel(
    const float* __restrict__ B1, const float* __restrict__ W2,
    float* __restrict__ ws, float* __restrict__ out)
{
    __shared__ s16x8 L[2][4][128][4];   // [buf][Ah,Am,Bh,Bm][row][slot16B] = 64 KB
    const int tid = threadIdx.x, bid = blockIdx.x;

    if (bid >= 256) {
        // ---- zero role: 256 blocks x 512 thr x 192 f32x4 = 402.7 MB ----
        const int zid = bid - 256;
        f32x4* p = (f32x4*)out + (size_t)zid * 98304 + tid;
        f32x4 z = (f32x4)0.0f;
#pragma unroll 8
        for (int i = 0; i < 192; ++i) { __builtin_nontemporal_store(z, p); p += 512; }
        return;
    }

    // ---- GEMM role ----
    const int cl = bid & 7, q = bid >> 3;      // cluster (XCD), within-cluster idx
    const int m0 = (cl * 4 + (q & 3)) * 128;   // 4 m-tiles per cluster
    const int n0 = (q >> 2) * 128;             // all 8 n-slices per cluster
    const int wave = tid >> 6, lane = tid & 63;
    const int wr = wave >> 1, wc = wave & 1;   // 4x2 wave grid
    const int fr = lane & 15, fk = lane >> 4;

    const u16* XH = (const u16*)(ws + OXH_F);
    const u16* XM = (const u16*)(ws + OXM_F);
    const u16* WH = (const u16*)(ws + OWH_F);
    const u16* WM = (const u16*)(ws + OWM_F);

    // staging: wave stages subtile st (0:Ah 1:Am 2:Bh 3:Bm), half hf (64 rows).
    // pass i covers rows hf*64+i*16..+15; lane l -> row +(l>>2), slot l&3,
    // holding global 16B chunk (l&3)^(row&3); row&3 == (l>>2)&3.
    const int st = wave >> 1, hf = wave & 1;
    const int sr4 = lane >> 2;
    const int cg  = (lane & 3) ^ (sr4 & 3);
    const u16* sb = (st >= 2)
        ? (((st == 3) ? WM : WH) + (size_t)(n0 + hf * 64 + sr4) * HID + cg * 8)
        : (((st == 1) ? XM : XH) + (size_t)(m0 + hf * 64 + sr4) * HID + cg * 8);
    char* db0 = (char*)&L[0][st][0][0] + hf * 4096;

    f32x4 acc[2][4];
#pragma unroll
    for (int i = 0; i < 2; ++i)
#pragma unroll
        for (int j = 0; j < 4; ++j) acc[i][j] = (f32x4)0.0f;

    // prologue: stage tile 0 into buf 0 (4 passes x 1 KB per wave)
#pragma unroll
    for (int i = 0; i < 4; ++i)
        gload16(sb + (size_t)i * 16 * HID, db0 + i * 1024);
    __syncthreads();    // tile 0 resident

    for (int kk = 0; kk < 32; ++kk) {
        const int b = kk & 1;
        if (kk + 1 < 32) {
            // next tile's staging; latency hides under this tile's MFMAs
            const u16* s = sb + (size_t)(kk + 1) * 32;
            char* d = db0 + (b ^ 1) * 32768;
#pragma unroll
            for (int i = 0; i < 4; ++i)
                gload16(s + (size_t)i * 16 * HID, d + i * 1024);
        }

        const s16x8 (*LAh)[4] = L[b][0];
        const s16x8 (*LAm)[4] = L[b][1];
        const s16x8 (*LBh)[4] = L[b][2];
        const s16x8 (*LBm)[4] = L[b][3];
        const int sl = fk ^ (fr & 3);          // row&3 == fr&3 for all frag rows
        s16x8 bh[4], bm[4];
#pragma unroll
        for (int j = 0; j < 4; ++j) {
            const int rb = wc * 64 + j * 16 + fr;
            bh[j] = LBh[rb][sl];
            bm[j] = LBm[rb][sl];
        }
#pragma unroll
        for (int i = 0; i < 2; ++i) {
            const int ra = wr * 32 + i * 16 + fr;
            s16x8 ah = LAh[ra][sl];
            s16x8 am = LAm[ra][sl];
#pragma unroll
            for (int j = 0; j < 4; ++j) {
                acc[i][j] = __builtin_amdgcn_mfma_f32_16x16x32_bf16(ah, bh[j], acc[i][j], 0, 0, 0);
                acc[i][j] = __builtin_amdgcn_mfma_f32_16x16x32_bf16(ah, bm[j], acc[i][j], 0, 0, 0);
                acc[i][j] = __builtin_amdgcn_mfma_f32_16x16x32_bf16(am, bh[j], acc[i][j], 0, 0, 0);
            }
        }
        __syncthreads();   // next tile staged + buf b reads done
    }

    // ---- epilogue: bias+relu, layer-2 partials over this wave's 64 cols ----
    // C/D: lane holds D[fk*4+r][fr] per 16x16 frag
    const int colbase = n0 + wc * 64 + fr;
#pragma unroll
    for (int j = 0; j < 4; ++j) {
        const float bj = B1[colbase + j * 16];
#pragma unroll
        for (int i = 0; i < 2; ++i)
#pragma unroll
            for (int r = 0; r < 4; ++r)
                acc[i][j][r] = fmaxf(acc[i][j][r] + bj, 0.f);
    }

    const int slice = (n0 >> 7) * 2 + wc;      // n-slice derived from n0 (remap-safe)
    float* pbase = ws + ((size_t)slice * NTOK + (m0 + wr * 32 + fk * 4)) * NEXP;
#pragma unroll
    for (int e = 0; e < 8; ++e) {
        const float w20 = W2[e * HID + colbase];
        const float w21 = W2[e * HID + colbase + 16];
        const float w22 = W2[e * HID + colbase + 32];
        const float w23 = W2[e * HID + colbase + 48];
        float pe[8];
#pragma unroll
        for (int i = 0; i < 2; ++i)
#pragma unroll
            for (int r = 0; r < 4; ++r)
                pe[i * 4 + r] = acc[i][0][r] * w20 + acc[i][1][r] * w21 +
                                acc[i][2][r] * w22 + acc[i][3][r] * w23;
#pragma unroll
        for (int m = 1; m <= 8; m <<= 1)
#pragma unroll
            for (int q2 = 0; q2 < 8; ++q2)
                pe[q2] += __shfl_xor(pe[q2], m, 64);
        if (fr == 0) {
#pragma unroll
            for (int i = 0; i < 2; ++i)
#pragma unroll
                for (int r = 0; r < 4; ++r)
                    pbase[(size_t)(i * 16 + r) * NEXP + e] = pe[i * 4 + r];
        }
    }
}

// ---------------- Router: sum partials, softmax, top-2, scatter ----------------
__global__ __launch_bounds__(256) void router2_kernel(
    const float* __restrict__ ws, const float* __restrict__ B2, float* __restrict__ out)
{
    const int t = blockIdx.x * 256 + threadIdx.x;
    float lg[8];
#pragma unroll
    for (int e = 0; e < 8; ++e) lg[e] = 0.f;
#pragma unroll
    for (int s = 0; s < 16; ++s) {      // fixed order -> deterministic
        const float* p = ws + ((size_t)s * NTOK + t) * NEXP;
        f32x4 v0 = *(const f32x4*)p;
        f32x4 v1 = *(const f32x4*)(p + 4);
        lg[0] += v0.x; lg[1] += v0.y; lg[2] += v0.z; lg[3] += v0.w;
        lg[4] += v1.x; lg[5] += v1.y; lg[6] += v1.z; lg[7] += v1.w;
    }
#pragma unroll
    for (int e = 0; e < 8; ++e) lg[e] += B2[e];

    float mx = lg[0];
#pragma unroll
    for (int e = 1; e < 8; ++e) mx = fmaxf(mx, lg[e]);
    float pr[8], s = 0.f;
#pragma unroll
    for (int e = 0; e < 8; ++e) { pr[e] = expf(lg[e] - mx); s += pr[e]; }
    const float inv = 1.f / s;
#pragma unroll
    for (int e = 0; e < 8; ++e) pr[e] *= inv;

    // top-2 (strict > : lowest index wins exact ties, matching lax.top_k)
    int e1 = 0; float p1 = pr[0];
#pragma unroll
    for (int e = 1; e < 8; ++e) if (pr[e] > p1) { p1 = pr[e]; e1 = e; }
    int e2 = -1; float p2 = -1.f;
#pragma unroll
    for (int e = 0; e < 8; ++e) if (e != e1 && pr[e] > p2) { p2 = pr[e]; e2 = e; }

    const float invs = 1.f / (p1 + p2);
    float* rp = out + RP_OFF + (size_t)t * NEXP;
    f32x4 o0 = {pr[0], pr[1], pr[2], pr[3]};
    f32x4 o1 = {pr[4], pr[5], pr[6], pr[7]};
    *(f32x4*)rp = o0; *(f32x4*)(rp + 4) = o1;

    const size_t base = (size_t)t * NEXP;
    out[DISP_OFF + (base + e1) * CAP] = 1.0f;
    out[DISP_OFF + (base + e2) * CAP] = 1.0f;
    out[COMB_OFF + (base + e1) * CAP] = p1 * invs;
    out[COMB_OFF + (base + e2) * CAP] = p2 * invs;
}

// ---------------- Aux loss ----------------
__global__ __launch_bounds__(256) void aux_kernel(float* __restrict__ out)
{
    __shared__ float sm[NEXP][257];
    const int tid = threadIdx.x;
    float s[NEXP];
#pragma unroll
    for (int e = 0; e < 8; ++e) s[e] = 0.f;
    const float* rp = out + RP_OFF;
    for (int t = tid; t < NTOK; t += 256) {
        f32x4 v0 = *(const f32x4*)&rp[(size_t)t * NEXP];
        f32x4 v1 = *(const f32x4*)&rp[(size_t)t * NEXP + 4];
        s[0] += v0.x; s[1] += v0.y; s[2] += v0.z; s[3] += v0.w;
        s[4] += v1.x; s[5] += v1.y; s[6] += v1.z; s[7] += v1.w;
    }
#pragma unroll
    for (int e = 0; e < 8; ++e) sm[e][tid] = s[e];
    __syncthreads();
    for (int st = 128; st > 0; st >>= 1) {
        if (tid < st) {
#pragma unroll
            for (int e = 0; e < 8; ++e) sm[e][tid] += sm[e][tid + st];
        }
        __syncthreads();
    }
    if (tid == 0) {
        float loss = 0.f;
#pragma unroll
        for (int e = 0; e < 8; ++e) {
            float m = sm[e][0] * (1.0f / NTOK);
            loss += m * logf(m * (float)NEXP + 1e-9f);
        }
        out[AUX_OFF] = loss;
    }
}

extern "C" void kernel_launch(void* const* d_in, const int* in_sizes, int n_in,
                              void* d_out, int out_size, void* d_ws, size_t ws_size,
                              hipStream_t stream)
{
    const float* x  = (const float*)d_in[0];
    const float* w1 = (const float*)d_in[1];
    const float* b1 = (const float*)d_in[2];
    const float* w2 = (const float*)d_in[3];
    const float* b2 = (const float*)d_in[4];
    float* out = (float*)d_out;
    float* ws  = (float*)d_ws;     // ~23 MB used

    prep_kernel<<<2560, 256, 0, stream>>>(x, w1, ws);
    // 512 blocks x 512 thr: 256 XCD-clustered GEMM tiles + 256 zero slices,
    // one of each co-resident per CU.
    fused_kernel<<<512, 512, 0, stream>>>(b1, w2, ws, out);
    router2_kernel<<<16, 256, 0, stream>>>(ws, b2, out);
    aux_kernel<<<1, 256, 0, stream>>>(out);
}